// Round 2
// baseline (1331.279 us; speedup 1.0000x reference)
//
#include <hip/hip_runtime.h>
#include <cmath>

// PropConv: K=10 hop gated propagation on a fixed graph + output MLP.
// R9: two memory-model fixes.
// (1) Agent-scope atomics execute MEMORY-SIDE on gfx950 (deg WRITE_SIZE was
//     99.6MB for 400KB of counters = 3.2M x 32B). Degree counting now uses
//     per-XCD replica counters (HW_REG_XCC_ID) + workgroup-scope atomics,
//     which RMW in the local XCD L2; a reduce kernel sums the 16 replicas.
//     Cross-kernel visibility is guaranteed by the end-of-dispatch L2 flush.
// (2) Hops are column-chunked 4 x 32 cols: the 10-hop recursion is
//     column-independent, and a 32-col bf16 state chunk is 3.2MB < 4MB/XCD
//     L2, so ALL blocks gather from an L2-resident region (no scheduling
//     coherence needed). Gathers move from ~7TB/s L3 to ~35TB/s L2.
//     feat0 is pre-transposed chunk-major into d_out (free until final MLP).

#define NNODES 50000
#define NEDGES 1600000
#define DD 128
#define KHOPS 10
#define ALPHA 0.1f

typedef short short8 __attribute__((ext_vector_type(8)));
typedef float f32x4 __attribute__((ext_vector_type(4)));

static __device__ __forceinline__ unsigned bf16rne(float x) {
    unsigned u = __float_as_uint(x);
    return (u + 0x7FFFu + ((u >> 16) & 1u)) >> 16;
}
static __device__ __forceinline__ float bf_lo(unsigned w) { return __uint_as_float(w << 16); }
static __device__ __forceinline__ float bf_hi(unsigned w) { return __uint_as_float(w & 0xFFFF0000u); }

// Physical XCD id (0..7). HW_REG_XCC_ID = 20, offset 0, size 4 -> imm 0x1814.
static __device__ __forceinline__ int xcc_id() {
    return (int)(__builtin_amdgcn_s_getreg((3 << 11) | 20) & 7u);
}

// 8-entry gate table: gate MLP has only 8 distinct inputs (etypes).
__global__ void gate_kernel(const float* __restrict__ emb, const float* __restrict__ We1,
                            const float* __restrict__ be1, const float* __restrict__ We2,
                            const float* __restrict__ be2, float* __restrict__ gate) {
    int t = threadIdx.x;
    if (t >= 8) return;
    float acc2 = 0.0f;
    for (int j = 0; j < 32; j++) {
        float a = be1[j];
        for (int k = 0; k < DD; k++) a += emb[t * DD + k] * We1[k * 32 + j];
        float g = 0.5f * a * (1.0f + erff(a * 0.70710678118654752f));  // exact GELU
        acc2 += g * We2[j];
    }
    acc2 += be2[0];
    gate[t] = 1.0f + 1.0f / (1.0f + expf(-acc2));   // 1 + sigmoid
}

// Degree histograms via per-XCD replicas + L2-local (workgroup-scope) atomics.
// cnt8 layout: [0..7][N] = incnt replicas, [8..15][N] = outcnt replicas.
// Replica x is only ever updated from XCD x -> single L2 is the RMW point.
__global__ __launch_bounds__(256) void deg_kernel(const int* __restrict__ src,
                                                  const int* __restrict__ dst,
                                                  int* __restrict__ cnt8, int E) {
    int x = xcc_id();
    int t = blockIdx.x * blockDim.x + threadIdx.x;
    if (t * 2 >= E) return;
    int2 d = ((const int2*)dst)[t];
    int2 s = ((const int2*)src)[t];
    int* cin = cnt8 + (size_t)x * NNODES;
    int* cout = cnt8 + (size_t)(8 + x) * NNODES;
    __hip_atomic_fetch_add(&cin[d.x], 1, __ATOMIC_RELAXED, __HIP_MEMORY_SCOPE_WORKGROUP);
    __hip_atomic_fetch_add(&cin[d.y], 1, __ATOMIC_RELAXED, __HIP_MEMORY_SCOPE_WORKGROUP);
    __hip_atomic_fetch_add(&cout[s.x], 1, __ATOMIC_RELAXED, __HIP_MEMORY_SCOPE_WORKGROUP);
    __hip_atomic_fetch_add(&cout[s.y], 1, __ATOMIC_RELAXED, __HIP_MEMORY_SCOPE_WORKGROUP);
}

__global__ __launch_bounds__(256) void reduce_kernel(const int* __restrict__ cnt8,
                                                     int* __restrict__ incnt,
                                                     int* __restrict__ outcnt, int N) {
    int n = blockIdx.x * 256 + threadIdx.x;
    if (n >= N) return;
    int a = 0, b = 0;
#pragma unroll
    for (int x = 0; x < 8; x++) {
        a += cnt8[(size_t)x * NNODES + n];
        b += cnt8[(size_t)(8 + x) * NNODES + n];
    }
    incnt[n] = a;
    outcnt[n] = b;
}

// ---- 3-kernel multi-block exclusive scan of incnt -> row_ptr ----
__global__ __launch_bounds__(256) void scan1_kernel(const int* __restrict__ cnt,
                                                    int* __restrict__ excl,
                                                    int* __restrict__ bsum, int N) {
    __shared__ int sh[256];
    int t = threadIdx.x;
    int g = blockIdx.x * 256 + t;
    int v = (g < N) ? cnt[g] : 0;
    sh[t] = v;
    __syncthreads();
    for (int off = 1; off < 256; off <<= 1) {
        int u = 0;
        if (t >= off) u = sh[t - off];
        __syncthreads();
        sh[t] += u;
        __syncthreads();
    }
    if (g < N) excl[g] = sh[t] - v;          // exclusive within block
    if (t == 255) bsum[blockIdx.x] = sh[255];
}
__global__ __launch_bounds__(256) void scan2_kernel(int* __restrict__ bsum, int nb) {
    __shared__ int sh[256];
    int t = threadIdx.x;
    int v = (t < nb) ? bsum[t] : 0;
    sh[t] = v;
    __syncthreads();
    for (int off = 1; off < 256; off <<= 1) {
        int u = 0;
        if (t >= off) u = sh[t - off];
        __syncthreads();
        sh[t] += u;
        __syncthreads();
    }
    if (t < nb) bsum[t] = sh[t] - v;         // exclusive
}
// Also initializes cursor = row_ptr so scatter needs no row_ptr read.
__global__ __launch_bounds__(256) void scan3_kernel(const int* __restrict__ excl,
                                                    const int* __restrict__ bsum,
                                                    int* __restrict__ row_ptr,
                                                    int* __restrict__ cursor, int N, int E) {
    int g = blockIdx.x * 256 + threadIdx.x;
    if (g < N) {
        int v = excl[g] + bsum[g >> 8];
        row_ptr[g] = v;
        cursor[g] = v;
    }
    if (g == N) row_ptr[N] = E;
}

// Bucket edges by dst. 4B payload: src (16b) | etype (<<16).
// cursor atomic must stay agent-scope (global positions). 4 edges/thread:
// 4 independent chains at ~76% occupancy (8/thread starved occupancy).
__global__ __launch_bounds__(256) void scatter_kernel(const int* __restrict__ src,
                                                      const int* __restrict__ dst,
                                                      const int* __restrict__ ef,
                                                      int* __restrict__ cursor,
                                                      int* __restrict__ epay, int E) {
    int t = blockIdx.x * blockDim.x + threadIdx.x;
    if (t * 4 >= E) return;
    int4 d = ((const int4*)dst)[t];
    int4 s = ((const int4*)src)[t];
    int4 f = ((const int4*)ef)[t];
    int dv[4] = {d.x, d.y, d.z, d.w};
    int pv[4] = {s.x | (f.x << 16), s.y | (f.y << 16),
                 s.z | (f.z << 16), s.w | (f.w << 16)};
    int pos[4];
#pragma unroll
    for (int u = 0; u < 4; u++) pos[u] = atomicAdd(&cursor[dv[u]], 1);
#pragma unroll
    for (int u = 0; u < 4; u++) epay[pos[u]] = pv[u];
}

// Fused: g0 = bf16(feat * src_norm) in CHUNK-MAJOR layout [4][N][32 bf16],
// and f0T = feat in chunk-major f32 [4][N][32] (residual source for hops).
__global__ __launch_bounds__(256) void scale_kernel(const float* __restrict__ feat,
                                                    const int* __restrict__ outcnt,
                                                    unsigned* __restrict__ g0,
                                                    float* __restrict__ f0T, int N) {
    int i = blockIdx.x * blockDim.x + threadIdx.x;   // float4 id over N*32
    if (i >= N * 32) return;
    int row = i >> 5, w = i & 31;
    int c = w >> 3, k = w & 7;                       // chunk, float4 within chunk
    int oc = outcnt[row]; if (oc < 1) oc = 1;
    float sn = rsqrtf((float)oc);
    float4 v = ((const float4*)feat)[i];
    size_t cr = (size_t)c * N + row;
    ((float4*)f0T)[cr * 8 + k] = v;
    uint2 o;
    o.x = bf16rne(v.x * sn) | (bf16rne(v.y * sn) << 16);
    o.y = bf16rne(v.z * sn) | (bf16rne(v.w * sn) << 16);
    ((uint2*)g0)[cr * 8 + k] = o;
}

// One hop on one 32-col chunk. 8 lanes per node (uint2/lane = 64B row);
// 8-edge batches: payloads loaded coalesced, broadcast via shfl(width 8),
// 8 independent 64B gathers in flight. Gather target = 3.2MB chunk ->
// L2-resident on every XCD. Epilogue: h = .9*dn*agg + .1*f0; stores
// bf16(h*sn), last hop stores bf16(h).
__global__ __launch_bounds__(256) void hopc_kernel(const unsigned* __restrict__ gin_c,
                                                   const float* __restrict__ f0T_c,
                                                   const int* __restrict__ incnt,
                                                   const int* __restrict__ outcnt,
                                                   const float* __restrict__ gate_g,
                                                   const int* __restrict__ row_ptr,
                                                   const int* __restrict__ epay,
                                                   unsigned* __restrict__ gout_c,
                                                   int N, int last) {
    __shared__ float gateL[8];
    if (threadIdx.x < 8) gateL[threadIdx.x] = gate_g[threadIdx.x];
    __syncthreads();
    int grp = threadIdx.x >> 3;      // 0..31: node group
    int lane8 = threadIdx.x & 7;     // col slot (uint2 = 4 bf16 cols)
    int node = blockIdx.x * 32 + grp;
    if (node >= N) return;
    int beg = row_ptr[node], end = row_ptr[node + 1];
    const uint2* gp = (const uint2*)gin_c;           // row = 8 uint2
    float a0 = 0.f, a1 = 0.f, a2 = 0.f, a3 = 0.f;
    for (int base = beg; base < end; base += 8) {
        int n = end - base; if (n > 8) n = 8;
        int p = (lane8 < n) ? epay[base + lane8] : 0;
        if (n == 8) {
            int pj[8];
#pragma unroll
            for (int u = 0; u < 8; u++) pj[u] = __shfl(p, u, 8);
            uint2 v[8];
#pragma unroll
            for (int u = 0; u < 8; u++)
                v[u] = gp[(size_t)(pj[u] & 0xFFFF) * 8 + lane8];
#pragma unroll
            for (int u = 0; u < 8; u++) {
                float c = gateL[(unsigned)pj[u] >> 16];
                a0 += c * bf_lo(v[u].x); a1 += c * bf_hi(v[u].x);
                a2 += c * bf_lo(v[u].y); a3 += c * bf_hi(v[u].y);
            }
        } else {
            for (int j = 0; j < n; j++) {
                int pj = __shfl(p, j, 8);
                float c = gateL[(unsigned)pj >> 16];
                uint2 v = gp[(size_t)(pj & 0xFFFF) * 8 + lane8];
                a0 += c * bf_lo(v.x); a1 += c * bf_hi(v.x);
                a2 += c * bf_lo(v.y); a3 += c * bf_hi(v.y);
            }
        }
    }
    int ic = incnt[node]; if (ic < 1) ic = 1;
    float dn = rsqrtf((float)ic) * (1.0f - ALPHA);
    float4 fv = ((const float4*)f0T_c)[(size_t)node * 8 + lane8];
    float h0 = dn * a0 + ALPHA * fv.x;
    float h1 = dn * a1 + ALPHA * fv.y;
    float h2 = dn * a2 + ALPHA * fv.z;
    float h3 = dn * a3 + ALPHA * fv.w;
    float sc = 1.0f;
    if (!last) { int oc = outcnt[node]; if (oc < 1) oc = 1; sc = rsqrtf((float)oc); }
    uint2 o;
    o.x = bf16rne(h0 * sc) | (bf16rne(h1 * sc) << 16);
    o.y = bf16rne(h2 * sc) | (bf16rne(h3 * sc) << 16);
    ((uint2*)gout_c)[(size_t)node * 8 + lane8] = o;
}

// bf16 MFMA MLP layer: out[N,128] = act(in[N,128] @ W[128,128] + b).
// chunked=1: input rows live in chunk-major [4][N][32 bf16] layout.
#define ASTR 136
__global__ __launch_bounds__(256) void mlp_mfma_kernel(const unsigned short* __restrict__ in,
                                                       const float* __restrict__ W,
                                                       const float* __restrict__ bias,
                                                       void* __restrict__ outp,
                                                       int N, int mode, int chunked) {
    __shared__ unsigned short As[64 * ASTR];    // 17.4 KB
    __shared__ unsigned short Bs[128 * ASTR];   // 34.8 KB
    int tid = threadIdx.x;
    int row0 = blockIdx.x * 64;
    // stage A: 64 rows x 128 bf16 (clamp rows >= N)
    for (int i = tid; i < 64 * 16; i += 256) {
        int r = i >> 4, c8 = i & 15;
        int gr = row0 + r; if (gr >= N) gr = N - 1;
        uint4 v;
        if (chunked) {
            size_t u4 = ((size_t)(c8 >> 2) * N + gr) * 4 + (c8 & 3);
            v = ((const uint4*)in)[u4];
        } else {
            v = *(const uint4*)(in + (size_t)gr * DD + c8 * 8);
        }
        *(uint4*)&As[r * ASTR + c8 * 8] = v;
    }
    // stage B transposed: Bs[n][k] = bf16(W[k][n])
    for (int i = tid; i < 128 * 128; i += 256) {
        int k = i >> 7, n = i & 127;
        Bs[n * ASTR + k] = (unsigned short)bf16rne(W[i]);
    }
    __syncthreads();

    int wv = tid >> 6, lane = tid & 63;
    int m = lane & 15, quad = lane >> 4;
    const unsigned short* arow = &As[(16 * wv + m) * ASTR + quad * 8];
    f32x4 acc[8];
#pragma unroll
    for (int t = 0; t < 8; t++) {
        const unsigned short* brow = &Bs[(t * 16 + m) * ASTR + quad * 8];
        f32x4 c = {0.f, 0.f, 0.f, 0.f};
#pragma unroll
        for (int s = 0; s < 4; s++) {
            short8 a = *(const short8*)(arow + s * 32);
            short8 b = *(const short8*)(brow + s * 32);
            c = __builtin_amdgcn_mfma_f32_16x16x32_bf16(a, b, c, 0, 0, 0);
        }
        acc[t] = c;
    }
#pragma unroll
    for (int t = 0; t < 8; t++) {
        float bv = bias[t * 16 + m];
#pragma unroll
        for (int r = 0; r < 4; r++) {
            int grow = row0 + 16 * wv + quad * 4 + r;
            if (grow >= N) continue;
            float v = acc[t][r] + bv;
            size_t oidx = (size_t)grow * DD + t * 16 + m;
            if (mode == 0) {
                v = 0.5f * v * (1.0f + erff(v * 0.70710678118654752f));
                ((unsigned short*)outp)[oidx] = (unsigned short)bf16rne(v);
            } else {
                ((float*)outp)[oidx] = v;
            }
        }
    }
}

extern "C" void kernel_launch(void* const* d_in, const int* in_sizes, int n_in,
                              void* d_out, int out_size, void* d_ws, size_t ws_size,
                              hipStream_t stream) {
    const float* feat = (const float*)d_in[0];
    const int*   e_feat = (const int*)d_in[1];
    const int*   src = (const int*)d_in[2];
    const int*   dst = (const int*)d_in[3];
    const float* emb = (const float*)d_in[4];
    const float* We1 = (const float*)d_in[5];
    const float* be1 = (const float*)d_in[6];
    const float* We2 = (const float*)d_in[7];
    const float* be2 = (const float*)d_in[8];
    const float* W1  = (const float*)d_in[9];
    const float* b1  = (const float*)d_in[10];
    const float* W2  = (const float*)d_in[11];
    const float* b2  = (const float*)d_in[12];
    float* out = (float*)d_out;

    const int N = NNODES, E = NEDGES;
    const int NBLK = (N + 255) / 256;     // 196 scan blocks
    char* ws = (char*)d_ws;
    size_t off = 0;
    unsigned* ga = (unsigned*)(ws + off);  off += (size_t)N * 256;    // 12.8 MB chunked bf16 state
    unsigned* gb = (unsigned*)(ws + off);  off += (size_t)N * 256;    // 12.8 MB chunked bf16 state
    int*   epay = (int*)(ws + off);        off += (size_t)E * 4;      // 6.4 MB
    int*   row_ptr = (int*)(ws + off);     off += (size_t)(N + 1) * 4;
    int*   excl = (int*)(ws + off);        off += (size_t)N * 4;
    int*   bsum = (int*)(ws + off);        off += 256 * 4;
    int*   cnts = (int*)(ws + off);        off += (size_t)3 * N * 4;  // incnt|outcnt|cursor
    int*   cnt8 = (int*)(ws + off);        off += (size_t)16 * N * 4; // 3.2 MB per-XCD replicas
    float* gate = (float*)(ws + off);      off += 64;
    int* incnt  = cnts;
    int* outcnt = cnts + N;
    int* cursor = cnts + 2 * N;
    float* f0T = out;   // 25.6 MB chunk-major f32 feat0; d_out is free until final MLP

    hipMemsetAsync(cnt8, 0, (size_t)16 * N * 4, stream);
    gate_kernel<<<1, 64, 0, stream>>>(emb, We1, be1, We2, be2, gate);
    deg_kernel<<<(E / 2 + 255) / 256, 256, 0, stream>>>(src, dst, cnt8, E);
    reduce_kernel<<<(N + 255) / 256, 256, 0, stream>>>(cnt8, incnt, outcnt, N);
    scan1_kernel<<<NBLK, 256, 0, stream>>>(incnt, excl, bsum, N);
    scan2_kernel<<<1, 256, 0, stream>>>(bsum, NBLK);
    scan3_kernel<<<(N + 256) / 256 + 1, 256, 0, stream>>>(excl, bsum, row_ptr, cursor, N, E);
    scatter_kernel<<<(E / 4 + 255) / 256, 256, 0, stream>>>(src, dst, e_feat, cursor, epay, E);
    scale_kernel<<<(N * 32 + 255) / 256, 256, 0, stream>>>(feat, outcnt, ga, f0T, N);

    // chunk-outer, hop-inner: every launch's gather target is one 3.2MB chunk
    for (int c = 0; c < 4; c++) {
        const unsigned* gin = ga + (size_t)c * N * 16;   // chunk stride = N*64B
        unsigned* gout = (unsigned*)(gb + (size_t)c * N * 16);
        const float* f0c = f0T + (size_t)c * N * 32;
        for (int k = 0; k < KHOPS; k++) {
            int last = (k == KHOPS - 1);
            hopc_kernel<<<(N + 31) / 32, 256, 0, stream>>>(gin, f0c, incnt, outcnt, gate,
                                                           row_ptr, epay, gout, N, last);
            const unsigned* tmp = gin;
            gin = gout;
            gout = (unsigned*)tmp;
        }
    }
    // 10 hops (even) -> final unscaled bf16 state in ga (chunk-major).
    unsigned short* hidden = (unsigned short*)gb;        // row-major [N][128] bf16
    mlp_mfma_kernel<<<(N + 63) / 64, 256, 0, stream>>>((const unsigned short*)ga, W1, b1,
                                                       hidden, N, 0, 1);
    mlp_mfma_kernel<<<(N + 63) / 64, 256, 0, stream>>>(hidden, W2, b2, out, N, 1, 0);
}

// Round 4
// 922.625 us; speedup vs baseline: 1.4429x; 1.4429x over previous
//
#include <hip/hip_runtime.h>
#include <cmath>

// PropConv: K=10 hop gated propagation on a fixed graph + output MLP.
// R11: fix R10's correctness bug. R10 assumed the same edge maps to the same
// XCD in deg_kernel and scatter_kernel (two different dispatches) -- undefined
// per the dispatch model, and it broke (absmax 0.07). Fix: the workgroup-scope
// fetch_add in deg_kernel ALREADY returns each edge's within-XCD-replica rank;
// record erank[e] = rank | (xcd<<24) (coalesced store). scatter then computes
// pos = base8[x_e][d] + rank_e with NO atomics at all -- x_e is the XCD
// recorded at count time, so positions are deterministic and unique under any
// scheduling. base8 = per-XCD exclusive prefix of cnt8 within each bucket
// (scan3, unchanged). Bucket-internal permutation is fine (segment-sum is
// order-independent). Hops stay in the proven R7 32-lane unchunked form
// (~7TB/s L3 random-gather ceiling, 256B/edge irreducible at bf16).

#define NNODES 50000
#define NEDGES 1600000
#define DD 128
#define KHOPS 10
#define ALPHA 0.1f

typedef short short8 __attribute__((ext_vector_type(8)));
typedef float f32x4 __attribute__((ext_vector_type(4)));

static __device__ __forceinline__ unsigned bf16rne(float x) {
    unsigned u = __float_as_uint(x);
    return (u + 0x7FFFu + ((u >> 16) & 1u)) >> 16;
}
static __device__ __forceinline__ float bf_lo(unsigned w) { return __uint_as_float(w << 16); }
static __device__ __forceinline__ float bf_hi(unsigned w) { return __uint_as_float(w & 0xFFFF0000u); }

// Physical XCD id (0..7): HW_REG_XCC_ID = reg 20, size 4 bits.
static __device__ __forceinline__ int xcc_id() {
    return (int)(__builtin_amdgcn_s_getreg((3 << 11) | 20) & 7u);
}

// 8-entry gate table: gate MLP has only 8 distinct inputs (etypes).
__global__ void gate_kernel(const float* __restrict__ emb, const float* __restrict__ We1,
                            const float* __restrict__ be1, const float* __restrict__ We2,
                            const float* __restrict__ be2, float* __restrict__ gate) {
    int t = threadIdx.x;
    if (t >= 8) return;
    float acc2 = 0.0f;
    for (int j = 0; j < 32; j++) {
        float a = be1[j];
        for (int k = 0; k < DD; k++) a += emb[t * DD + k] * We1[k * 32 + j];
        float g = 0.5f * a * (1.0f + erff(a * 0.70710678118654752f));  // exact GELU
        acc2 += g * We2[j];
    }
    acc2 += be2[0];
    gate[t] = 1.0f + 1.0f / (1.0f + expf(-acc2));   // 1 + sigmoid
}

// Degree histograms via per-XCD replicas + L2-local (workgroup-scope) atomics.
// cnt8 layout: [0..7][N] = incnt replicas, [8..15][N] = outcnt replicas.
// The in-degree fetch_add's RETURN VALUE is the edge's within-replica rank;
// erank[e] = rank | (xcd << 24) makes scatter's position deterministic.
__global__ __launch_bounds__(256) void deg_kernel(const int* __restrict__ src,
                                                  const int* __restrict__ dst,
                                                  int* __restrict__ cnt8,
                                                  int* __restrict__ erank, int E) {
    int x = xcc_id();
    int t = blockIdx.x * blockDim.x + threadIdx.x;
    if (t * 2 >= E) return;
    int2 d = ((const int2*)dst)[t];
    int2 s = ((const int2*)src)[t];
    int* cin = cnt8 + (size_t)x * NNODES;
    int* cout = cnt8 + (size_t)(8 + x) * NNODES;
    int r0 = __hip_atomic_fetch_add(&cin[d.x], 1, __ATOMIC_RELAXED, __HIP_MEMORY_SCOPE_WORKGROUP);
    int r1 = __hip_atomic_fetch_add(&cin[d.y], 1, __ATOMIC_RELAXED, __HIP_MEMORY_SCOPE_WORKGROUP);
    __hip_atomic_fetch_add(&cout[s.x], 1, __ATOMIC_RELAXED, __HIP_MEMORY_SCOPE_WORKGROUP);
    __hip_atomic_fetch_add(&cout[s.y], 1, __ATOMIC_RELAXED, __HIP_MEMORY_SCOPE_WORKGROUP);
    int2 r;
    r.x = r0 | (x << 24);
    r.y = r1 | (x << 24);
    ((int2*)erank)[t] = r;
}

__global__ __launch_bounds__(256) void reduce_kernel(const int* __restrict__ cnt8,
                                                     int* __restrict__ incnt,
                                                     int* __restrict__ outcnt, int N) {
    int n = blockIdx.x * 256 + threadIdx.x;
    if (n >= N) return;
    int a = 0, b = 0;
#pragma unroll
    for (int x = 0; x < 8; x++) {
        a += cnt8[(size_t)x * NNODES + n];
        b += cnt8[(size_t)(8 + x) * NNODES + n];
    }
    incnt[n] = a;
    outcnt[n] = b;
}

// ---- 3-kernel multi-block exclusive scan of incnt -> row_ptr ----
__global__ __launch_bounds__(256) void scan1_kernel(const int* __restrict__ cnt,
                                                    int* __restrict__ excl,
                                                    int* __restrict__ bsum, int N) {
    __shared__ int sh[256];
    int t = threadIdx.x;
    int g = blockIdx.x * 256 + t;
    int v = (g < N) ? cnt[g] : 0;
    sh[t] = v;
    __syncthreads();
    for (int off = 1; off < 256; off <<= 1) {
        int u = 0;
        if (t >= off) u = sh[t - off];
        __syncthreads();
        sh[t] += u;
        __syncthreads();
    }
    if (g < N) excl[g] = sh[t] - v;          // exclusive within block
    if (t == 255) bsum[blockIdx.x] = sh[255];
}
__global__ __launch_bounds__(256) void scan2_kernel(int* __restrict__ bsum, int nb) {
    __shared__ int sh[256];
    int t = threadIdx.x;
    int v = (t < nb) ? bsum[t] : 0;
    sh[t] = v;
    __syncthreads();
    for (int off = 1; off < 256; off <<= 1) {
        int u = 0;
        if (t >= off) u = sh[t - off];
        __syncthreads();
        sh[t] += u;
        __syncthreads();
    }
    if (t < nb) bsum[t] = sh[t] - v;         // exclusive
}
// row_ptr + per-XCD sub-range bases: base8[x][d] = row_ptr[d] +
// sum_{y<x} cnt8[y][d]. Sub-ranges partition each dst bucket.
__global__ __launch_bounds__(256) void scan3_kernel(const int* __restrict__ excl,
                                                    const int* __restrict__ bsum,
                                                    const int* __restrict__ cnt8,
                                                    int* __restrict__ row_ptr,
                                                    int* __restrict__ base8, int N, int E) {
    int g = blockIdx.x * 256 + threadIdx.x;
    if (g < N) {
        int v = excl[g] + bsum[g >> 8];
        row_ptr[g] = v;
        int run = v;
#pragma unroll
        for (int x = 0; x < 8; x++) {
            base8[(size_t)x * NNODES + g] = run;
            run += cnt8[(size_t)x * NNODES + g];
        }
    }
    if (g == N) row_ptr[N] = E;
}

// Bucket edges by dst. 4B payload: src (16b) | etype (<<16).
// NO atomics: pos = base8[x_e][d] + rank_e with (x_e, rank_e) recorded by
// deg_kernel. base8 is 1.6MB -> L2-resident random reads. 4 edges/thread.
__global__ __launch_bounds__(256) void scatter_kernel(const int* __restrict__ src,
                                                      const int* __restrict__ dst,
                                                      const int* __restrict__ ef,
                                                      const int* __restrict__ erank,
                                                      const int* __restrict__ base8,
                                                      int* __restrict__ epay, int E) {
    int t = blockIdx.x * blockDim.x + threadIdx.x;
    if (t * 4 >= E) return;
    int4 d = ((const int4*)dst)[t];
    int4 s = ((const int4*)src)[t];
    int4 f = ((const int4*)ef)[t];
    int4 r = ((const int4*)erank)[t];
    int dv[4] = {d.x, d.y, d.z, d.w};
    int rv[4] = {r.x, r.y, r.z, r.w};
    int pv[4] = {s.x | (f.x << 16), s.y | (f.y << 16),
                 s.z | (f.z << 16), s.w | (f.w << 16)};
    int pos[4];
#pragma unroll
    for (int u = 0; u < 4; u++) {
        int x = (unsigned)rv[u] >> 24;
        int rk = rv[u] & 0xFFFFFF;
        pos[u] = base8[(size_t)x * NNODES + dv[u]] + rk;
    }
#pragma unroll
    for (int u = 0; u < 4; u++) epay[pos[u]] = pv[u];
}

// g0 = bf16(feat * src_norm), row-major [N][128] bf16 (256B rows).
__global__ void scale_kernel(const float* __restrict__ feat, const int* __restrict__ outcnt,
                             unsigned* __restrict__ g0, int N) {
    int i = blockIdx.x * blockDim.x + threadIdx.x;   // one float4-group (4 cols)
    if (i >= N * 32) return;
    int row = i >> 5;
    int oc = outcnt[row]; if (oc < 1) oc = 1;
    float sn = rsqrtf((float)oc);
    float4 v = ((const float4*)feat)[i];
    uint2 o;
    o.x = bf16rne(v.x * sn) | (bf16rne(v.y * sn) << 16);
    o.y = bf16rne(v.z * sn) | (bf16rne(v.w * sn) << 16);
    ((uint2*)g0)[i] = o;
}

// Half-wave (32 lanes) per dst node; lane holds uint2 = 4 bf16 cols of the
// 256B row. Payloads loaded coalesced in chunks of 32, broadcast via __shfl;
// x8 unroll -> 8 independent 8B gathers in flight per lane. Epilogue in f32:
// h = .9*dstn*agg + .1*feat0; stores bf16(h*srcn); last hop stores bf16(h).
__global__ __launch_bounds__(256) void hop_kernel(const unsigned* __restrict__ g_in,
                                                  const float* __restrict__ feat0,
                                                  const int* __restrict__ incnt,
                                                  const int* __restrict__ outcnt,
                                                  const float* __restrict__ gate_g,
                                                  const int* __restrict__ row_ptr,
                                                  const int* __restrict__ epay,
                                                  unsigned* __restrict__ g_out,
                                                  int N, int last) {
    __shared__ float gateL[8];
    if (threadIdx.x < 8) gateL[threadIdx.x] = gate_g[threadIdx.x];
    __syncthreads();
    int half = threadIdx.x >> 5;     // 0..7
    int lane = threadIdx.x & 31;
    int node = blockIdx.x * 8 + half;
    if (node >= N) return;
    int beg = row_ptr[node], end = row_ptr[node + 1];
    const uint2* gp = (const uint2*)g_in;            // row = 32 uint2
    float a0 = 0.f, a1 = 0.f, a2 = 0.f, a3 = 0.f;
    for (int base = beg; base < end; base += 32) {
        int n = end - base; if (n > 32) n = 32;
        int p = 0;
        if (lane < n) p = epay[base + lane];
        int j = 0;
        for (; j + 8 <= n; j += 8) {
            int pj[8];
#pragma unroll
            for (int u = 0; u < 8; u++) pj[u] = __shfl(p, j + u, 32);
            uint2 v[8];
#pragma unroll
            for (int u = 0; u < 8; u++)
                v[u] = gp[(size_t)(pj[u] & 0xFFFF) * 32 + lane];
#pragma unroll
            for (int u = 0; u < 8; u++) {
                float c = gateL[(unsigned)pj[u] >> 16];
                a0 += c * bf_lo(v[u].x); a1 += c * bf_hi(v[u].x);
                a2 += c * bf_lo(v[u].y); a3 += c * bf_hi(v[u].y);
            }
        }
        for (; j < n; j++) {
            int pj = __shfl(p, j, 32);
            float c = gateL[(unsigned)pj >> 16];
            uint2 v = gp[(size_t)(pj & 0xFFFF) * 32 + lane];
            a0 += c * bf_lo(v.x); a1 += c * bf_hi(v.x);
            a2 += c * bf_lo(v.y); a3 += c * bf_hi(v.y);
        }
    }
    int ic = incnt[node]; if (ic < 1) ic = 1;
    float dn = rsqrtf((float)ic) * (1.0f - ALPHA);
    float4 fv = *(const float4*)(feat0 + (size_t)node * DD + lane * 4);
    float h0 = dn * a0 + ALPHA * fv.x;
    float h1 = dn * a1 + ALPHA * fv.y;
    float h2 = dn * a2 + ALPHA * fv.z;
    float h3 = dn * a3 + ALPHA * fv.w;
    float sc = 1.0f;
    if (!last) { int oc = outcnt[node]; if (oc < 1) oc = 1; sc = rsqrtf((float)oc); }
    uint2 o;
    o.x = bf16rne(h0 * sc) | (bf16rne(h1 * sc) << 16);
    o.y = bf16rne(h2 * sc) | (bf16rne(h3 * sc) << 16);
    ((uint2*)g_out)[(size_t)node * 32 + lane] = o;
}

// bf16 MFMA MLP layer: out[N,128] = act(in[N,128] @ W[128,128] + b).
// Block = 256 thr (4 waves), 64-row tile, full K=128 and all 128 cols.
// Verified gfx950 layouts: A[m=lane&15][k=quad*8+j], B[k][n=lane&15],
// D col=lane&15, row=quad*4+reg.
#define ASTR 136
__global__ __launch_bounds__(256) void mlp_mfma_kernel(const unsigned short* __restrict__ in,
                                                       const float* __restrict__ W,
                                                       const float* __restrict__ bias,
                                                       void* __restrict__ outp,
                                                       int N, int mode) {  // mode0: gelu+bf16 out; mode1: f32 out
    __shared__ unsigned short As[64 * ASTR];    // 17.4 KB
    __shared__ unsigned short Bs[128 * ASTR];   // 34.8 KB
    int tid = threadIdx.x;
    int row0 = blockIdx.x * 64;
    // stage A: 64 rows x 128 bf16 (clamp rows >= N)
    for (int i = tid; i < 64 * 16; i += 256) {
        int r = i >> 4, c8 = i & 15;
        int gr = row0 + r; if (gr >= N) gr = N - 1;
        uint4 v = *(const uint4*)(in + (size_t)gr * DD + c8 * 8);
        *(uint4*)&As[r * ASTR + c8 * 8] = v;
    }
    // stage B transposed: Bs[n][k] = bf16(W[k][n])
    for (int i = tid; i < 128 * 128; i += 256) {
        int k = i >> 7, n = i & 127;
        Bs[n * ASTR + k] = (unsigned short)bf16rne(W[i]);
    }
    __syncthreads();

    int wv = tid >> 6, lane = tid & 63;
    int m = lane & 15, quad = lane >> 4;
    const unsigned short* arow = &As[(16 * wv + m) * ASTR + quad * 8];
    f32x4 acc[8];
#pragma unroll
    for (int t = 0; t < 8; t++) {
        const unsigned short* brow = &Bs[(t * 16 + m) * ASTR + quad * 8];
        f32x4 c = {0.f, 0.f, 0.f, 0.f};
#pragma unroll
        for (int s = 0; s < 4; s++) {
            short8 a = *(const short8*)(arow + s * 32);
            short8 b = *(const short8*)(brow + s * 32);
            c = __builtin_amdgcn_mfma_f32_16x16x32_bf16(a, b, c, 0, 0, 0);
        }
        acc[t] = c;
    }
#pragma unroll
    for (int t = 0; t < 8; t++) {
        float bv = bias[t * 16 + m];
#pragma unroll
        for (int r = 0; r < 4; r++) {
            int grow = row0 + 16 * wv + quad * 4 + r;
            if (grow >= N) continue;
            float v = acc[t][r] + bv;
            size_t oidx = (size_t)grow * DD + t * 16 + m;
            if (mode == 0) {
                v = 0.5f * v * (1.0f + erff(v * 0.70710678118654752f));
                ((unsigned short*)outp)[oidx] = (unsigned short)bf16rne(v);
            } else {
                ((float*)outp)[oidx] = v;
            }
        }
    }
}

extern "C" void kernel_launch(void* const* d_in, const int* in_sizes, int n_in,
                              void* d_out, int out_size, void* d_ws, size_t ws_size,
                              hipStream_t stream) {
    const float* feat = (const float*)d_in[0];
    const int*   e_feat = (const int*)d_in[1];
    const int*   src = (const int*)d_in[2];
    const int*   dst = (const int*)d_in[3];
    const float* emb = (const float*)d_in[4];
    const float* We1 = (const float*)d_in[5];
    const float* be1 = (const float*)d_in[6];
    const float* We2 = (const float*)d_in[7];
    const float* be2 = (const float*)d_in[8];
    const float* W1  = (const float*)d_in[9];
    const float* b1  = (const float*)d_in[10];
    const float* W2  = (const float*)d_in[11];
    const float* b2  = (const float*)d_in[12];
    float* out = (float*)d_out;

    const int N = NNODES, E = NEDGES;
    const int NBLK = (N + 255) / 256;     // 196 scan blocks
    char* ws = (char*)d_ws;
    size_t off = 0;
    unsigned* ga = (unsigned*)(ws + off);  off += (size_t)N * 256;    // 12.8 MB bf16 state
    unsigned* gb = (unsigned*)(ws + off);  off += (size_t)N * 256;    // 12.8 MB bf16 state
    int*   epay = (int*)(ws + off);        off += (size_t)E * 4;      // 6.4 MB
    int*   erank = (int*)(ws + off);       off += (size_t)E * 4;      // 6.4 MB per-edge (xcd,rank)
    int*   row_ptr = (int*)(ws + off);     off += (size_t)(N + 1) * 4;
    int*   excl = (int*)(ws + off);        off += (size_t)N * 4;
    int*   bsum = (int*)(ws + off);        off += 256 * 4;
    int*   cnts = (int*)(ws + off);        off += (size_t)2 * N * 4;  // incnt|outcnt
    int*   cnt8 = (int*)(ws + off);        off += (size_t)16 * N * 4; // 3.2 MB per-XCD replicas
    int*   base8 = (int*)(ws + off);       off += (size_t)8 * N * 4;  // 1.6 MB per-XCD bases
    float* gate = (float*)(ws + off);      off += 64;
    int* incnt  = cnts;
    int* outcnt = cnts + N;

    hipMemsetAsync(cnt8, 0, (size_t)16 * N * 4, stream);
    gate_kernel<<<1, 64, 0, stream>>>(emb, We1, be1, We2, be2, gate);
    deg_kernel<<<(E / 2 + 255) / 256, 256, 0, stream>>>(src, dst, cnt8, erank, E);
    reduce_kernel<<<(N + 255) / 256, 256, 0, stream>>>(cnt8, incnt, outcnt, N);
    scan1_kernel<<<NBLK, 256, 0, stream>>>(incnt, excl, bsum, N);
    scan2_kernel<<<1, 256, 0, stream>>>(bsum, NBLK);
    scan3_kernel<<<(N + 256) / 256 + 1, 256, 0, stream>>>(excl, bsum, cnt8, row_ptr,
                                                          base8, N, E);
    scatter_kernel<<<(E / 4 + 255) / 256, 256, 0, stream>>>(src, dst, e_feat, erank,
                                                            base8, epay, E);
    scale_kernel<<<(N * 32 + 255) / 256, 256, 0, stream>>>(feat, outcnt, ga, N);

    const unsigned* gin = ga;
    unsigned* gout = gb;
    for (int k = 0; k < KHOPS; k++) {
        int last = (k == KHOPS - 1);
        hop_kernel<<<(N + 7) / 8, 256, 0, stream>>>(gin, feat, incnt, outcnt, gate,
                                                    row_ptr, epay, gout, N, last);
        gin = gout;
        gout = (gout == ga) ? gb : ga;
    }
    // Final h (unscaled, bf16) is in ga (hop9 writes ga); gb is free -> hidden.
    const unsigned short* hfin = (const unsigned short*)gin;
    unsigned short* hidden = (unsigned short*)gout;
    mlp_mfma_kernel<<<(N + 63) / 64, 256, 0, stream>>>(hfin, W1, b1, hidden, N, 0);
    mlp_mfma_kernel<<<(N + 63) / 64, 256, 0, stream>>>(hidden, W2, b2, out, N, 1);
}

// Round 5
// 816.012 us; speedup vs baseline: 1.6314x; 1.1307x over previous
//
#include <hip/hip_runtime.h>
#include <cmath>

// PropConv: K=10 hop gated propagation on a fixed graph + output MLP.
// R12: eliminate ALL global atomics from preprocessing. R11 counters proved
// global atomics cost a ~32B memory-side RMW regardless of scope (deg: 3.2M
// atomics -> 105.9MB WRITE_SIZE, 150us, scope change R8->R11 made no diff).
// Replacement: LDS-histogram counting sort. Nodes partitioned into R=4
// ranges of 16384 (64KB LDS counters, 2 blocks/CU); edges into B=64 fixed
// slices. Pass1: block (r,b) streams slice b, LDS-atomics dsts (srcs) in
// range r, writes partial histogram cnt_in[b][n] (cnt_out) non-atomically.
// base_part[b][n] = row_ptr[n] + prefix_b(cnt_in) (deterministic: slice is a
// function of edge index, NOT scheduling -- no R10 XCD-assignment bug).
// Pass2: block (r,b) loads LDS cursors from base_part, re-streams slice b,
// pos = lds_fetch_add(cursor) -> epay[pos]. Zero global atomics anywhere.
// Hops unchanged (accepted ~7TB/s L3 random-gather ceiling, 256B/edge).

#define NNODES 50000
#define NEDGES 1600000
#define DD 128
#define KHOPS 10
#define ALPHA 0.1f

#define RS 16384          // node-range size (64KB LDS of int counters)
#define NRANGE 4          // ceil(50000/16384)
#define NSLICE 64         // edge slices
#define SLICE_E (NEDGES / NSLICE)   // 25000 edges/slice (100000B, 16B-aligned)

typedef short short8 __attribute__((ext_vector_type(8)));
typedef float f32x4 __attribute__((ext_vector_type(4)));

static __device__ __forceinline__ unsigned bf16rne(float x) {
    unsigned u = __float_as_uint(x);
    return (u + 0x7FFFu + ((u >> 16) & 1u)) >> 16;
}
static __device__ __forceinline__ float bf_lo(unsigned w) { return __uint_as_float(w << 16); }
static __device__ __forceinline__ float bf_hi(unsigned w) { return __uint_as_float(w & 0xFFFF0000u); }

// 8-entry gate table: gate MLP has only 8 distinct inputs (etypes).
__global__ void gate_kernel(const float* __restrict__ emb, const float* __restrict__ We1,
                            const float* __restrict__ be1, const float* __restrict__ We2,
                            const float* __restrict__ be2, float* __restrict__ gate) {
    int t = threadIdx.x;
    if (t >= 8) return;
    float acc2 = 0.0f;
    for (int j = 0; j < 32; j++) {
        float a = be1[j];
        for (int k = 0; k < DD; k++) a += emb[t * DD + k] * We1[k * 32 + j];
        float g = 0.5f * a * (1.0f + erff(a * 0.70710678118654752f));  // exact GELU
        acc2 += g * We2[j];
    }
    acc2 += be2[0];
    gate[t] = 1.0f + 1.0f / (1.0f + expf(-acc2));   // 1 + sigmoid
}

// Pass1a: per-(range,slice) in-degree partial histogram via LDS atomics.
// cnt[b][n] written non-atomically (includes zeros -> no memset needed).
__global__ __launch_bounds__(256) void hist_kernel(const int* __restrict__ key,
                                                   int* __restrict__ cnt) {
    __shared__ int h[RS];
    int b = blockIdx.x, r = blockIdx.y;
    int lo = r * RS;
    int hi = lo + RS; if (hi > NNODES) hi = NNODES;
    for (int i = threadIdx.x; i < RS; i += 256) h[i] = 0;
    __syncthreads();
    const int4* p = (const int4*)(key + b * SLICE_E);
    for (int i = threadIdx.x; i < SLICE_E / 4; i += 256) {
        int4 v = p[i];
        if (v.x >= lo && v.x < hi) atomicAdd(&h[v.x - lo], 1);
        if (v.y >= lo && v.y < hi) atomicAdd(&h[v.y - lo], 1);
        if (v.z >= lo && v.z < hi) atomicAdd(&h[v.z - lo], 1);
        if (v.w >= lo && v.w < hi) atomicAdd(&h[v.w - lo], 1);
    }
    __syncthreads();
    int n = hi - lo;
    for (int i = threadIdx.x; i < n; i += 256)
        cnt[(size_t)b * NNODES + lo + i] = h[i];
}

// Totals: incnt/outcnt[n] = sum over slices of partials (coalesced slabs).
__global__ __launch_bounds__(256) void reduce_kernel(const int* __restrict__ cnt_in,
                                                     const int* __restrict__ cnt_out,
                                                     int* __restrict__ incnt,
                                                     int* __restrict__ outcnt, int N) {
    int n = blockIdx.x * 256 + threadIdx.x;
    if (n >= N) return;
    int a = 0, b = 0;
    for (int x = 0; x < NSLICE; x++) {
        a += cnt_in[(size_t)x * NNODES + n];
        b += cnt_out[(size_t)x * NNODES + n];
    }
    incnt[n] = a;
    outcnt[n] = b;
}

// ---- 3-kernel multi-block exclusive scan of incnt -> row_ptr ----
__global__ __launch_bounds__(256) void scan1_kernel(const int* __restrict__ cnt,
                                                    int* __restrict__ excl,
                                                    int* __restrict__ bsum, int N) {
    __shared__ int sh[256];
    int t = threadIdx.x;
    int g = blockIdx.x * 256 + t;
    int v = (g < N) ? cnt[g] : 0;
    sh[t] = v;
    __syncthreads();
    for (int off = 1; off < 256; off <<= 1) {
        int u = 0;
        if (t >= off) u = sh[t - off];
        __syncthreads();
        sh[t] += u;
        __syncthreads();
    }
    if (g < N) excl[g] = sh[t] - v;          // exclusive within block
    if (t == 255) bsum[blockIdx.x] = sh[255];
}
__global__ __launch_bounds__(256) void scan2_kernel(int* __restrict__ bsum, int nb) {
    __shared__ int sh[256];
    int t = threadIdx.x;
    int v = (t < nb) ? bsum[t] : 0;
    sh[t] = v;
    __syncthreads();
    for (int off = 1; off < 256; off <<= 1) {
        int u = 0;
        if (t >= off) u = sh[t - off];
        __syncthreads();
        sh[t] += u;
        __syncthreads();
    }
    if (t < nb) bsum[t] = sh[t] - v;         // exclusive
}
__global__ __launch_bounds__(256) void scan3_kernel(const int* __restrict__ excl,
                                                    const int* __restrict__ bsum,
                                                    int* __restrict__ row_ptr, int N, int E) {
    int g = blockIdx.x * 256 + threadIdx.x;
    if (g < N) row_ptr[g] = excl[g] + bsum[g >> 8];
    if (g == N) row_ptr[N] = E;
}

// Per-slice bucket bases: base_part[b][n] = row_ptr[n] + sum_{b'<b} cnt_in[b'][n].
// Sub-ranges partition each dst bucket deterministically by slice.
__global__ __launch_bounds__(256) void base_kernel(const int* __restrict__ row_ptr,
                                                   const int* __restrict__ cnt_in,
                                                   int* __restrict__ base_part, int N) {
    int n = blockIdx.x * 256 + threadIdx.x;
    if (n >= N) return;
    int run = row_ptr[n];
    for (int b = 0; b < NSLICE; b++) {
        base_part[(size_t)b * NNODES + n] = run;
        run += cnt_in[(size_t)b * NNODES + n];
    }
}

// Pass2: bucket edges by dst with LDS cursors -- zero global atomics.
// Payload: src (16b) | etype (<<16). Block (r,b) re-streams slice b; each
// in-range edge gets pos = lds_fetch_add(cursor[dst-lo]). Positions are
// unique: cursor range for (b,n) is exactly cnt_in[b][n] wide.
__global__ __launch_bounds__(256) void scatter2_kernel(const int* __restrict__ src,
                                                       const int* __restrict__ dst,
                                                       const int* __restrict__ ef,
                                                       const int* __restrict__ base_part,
                                                       int* __restrict__ epay) {
    __shared__ int cur[RS];
    int b = blockIdx.x, r = blockIdx.y;
    int lo = r * RS;
    int hi = lo + RS; if (hi > NNODES) hi = NNODES;
    int n = hi - lo;
    for (int i = threadIdx.x; i < n; i += 256)
        cur[i] = base_part[(size_t)b * NNODES + lo + i];
    __syncthreads();
    int off = b * SLICE_E;
    const int4* pd = (const int4*)(dst + off);
    const int4* ps = (const int4*)(src + off);
    const int4* pf = (const int4*)(ef + off);
    for (int i = threadIdx.x; i < SLICE_E / 4; i += 256) {
        int4 d = pd[i];
        int4 s = ps[i];
        int4 f = pf[i];
        int dv[4] = {d.x, d.y, d.z, d.w};
        int sv[4] = {s.x, s.y, s.z, s.w};
        int fv[4] = {f.x, f.y, f.z, f.w};
#pragma unroll
        for (int u = 0; u < 4; u++) {
            if (dv[u] >= lo && dv[u] < hi) {
                int pos = atomicAdd(&cur[dv[u] - lo], 1);
                epay[pos] = sv[u] | (fv[u] << 16);
            }
        }
    }
}

// g0 = bf16(feat * src_norm), row-major [N][128] bf16 (256B rows).
__global__ void scale_kernel(const float* __restrict__ feat, const int* __restrict__ outcnt,
                             unsigned* __restrict__ g0, int N) {
    int i = blockIdx.x * blockDim.x + threadIdx.x;   // one float4-group (4 cols)
    if (i >= N * 32) return;
    int row = i >> 5;
    int oc = outcnt[row]; if (oc < 1) oc = 1;
    float sn = rsqrtf((float)oc);
    float4 v = ((const float4*)feat)[i];
    uint2 o;
    o.x = bf16rne(v.x * sn) | (bf16rne(v.y * sn) << 16);
    o.y = bf16rne(v.z * sn) | (bf16rne(v.w * sn) << 16);
    ((uint2*)g0)[i] = o;
}

// Half-wave (32 lanes) per dst node; lane holds uint2 = 4 bf16 cols of the
// 256B row. Payloads loaded coalesced in chunks of 32, broadcast via __shfl;
// x8 unroll -> 8 independent 8B gathers in flight per lane. Epilogue in f32:
// h = .9*dstn*agg + .1*feat0; stores bf16(h*srcn); last hop stores bf16(h).
__global__ __launch_bounds__(256) void hop_kernel(const unsigned* __restrict__ g_in,
                                                  const float* __restrict__ feat0,
                                                  const int* __restrict__ incnt,
                                                  const int* __restrict__ outcnt,
                                                  const float* __restrict__ gate_g,
                                                  const int* __restrict__ row_ptr,
                                                  const int* __restrict__ epay,
                                                  unsigned* __restrict__ g_out,
                                                  int N, int last) {
    __shared__ float gateL[8];
    if (threadIdx.x < 8) gateL[threadIdx.x] = gate_g[threadIdx.x];
    __syncthreads();
    int half = threadIdx.x >> 5;     // 0..7
    int lane = threadIdx.x & 31;
    int node = blockIdx.x * 8 + half;
    if (node >= N) return;
    int beg = row_ptr[node], end = row_ptr[node + 1];
    const uint2* gp = (const uint2*)g_in;            // row = 32 uint2
    float a0 = 0.f, a1 = 0.f, a2 = 0.f, a3 = 0.f;
    for (int base = beg; base < end; base += 32) {
        int n = end - base; if (n > 32) n = 32;
        int p = 0;
        if (lane < n) p = epay[base + lane];
        int j = 0;
        for (; j + 8 <= n; j += 8) {
            int pj[8];
#pragma unroll
            for (int u = 0; u < 8; u++) pj[u] = __shfl(p, j + u, 32);
            uint2 v[8];
#pragma unroll
            for (int u = 0; u < 8; u++)
                v[u] = gp[(size_t)(pj[u] & 0xFFFF) * 32 + lane];
#pragma unroll
            for (int u = 0; u < 8; u++) {
                float c = gateL[(unsigned)pj[u] >> 16];
                a0 += c * bf_lo(v[u].x); a1 += c * bf_hi(v[u].x);
                a2 += c * bf_lo(v[u].y); a3 += c * bf_hi(v[u].y);
            }
        }
        for (; j < n; j++) {
            int pj = __shfl(p, j, 32);
            float c = gateL[(unsigned)pj >> 16];
            uint2 v = gp[(size_t)(pj & 0xFFFF) * 32 + lane];
            a0 += c * bf_lo(v.x); a1 += c * bf_hi(v.x);
            a2 += c * bf_lo(v.y); a3 += c * bf_hi(v.y);
        }
    }
    int ic = incnt[node]; if (ic < 1) ic = 1;
    float dn = rsqrtf((float)ic) * (1.0f - ALPHA);
    float4 fv = *(const float4*)(feat0 + (size_t)node * DD + lane * 4);
    float h0 = dn * a0 + ALPHA * fv.x;
    float h1 = dn * a1 + ALPHA * fv.y;
    float h2 = dn * a2 + ALPHA * fv.z;
    float h3 = dn * a3 + ALPHA * fv.w;
    float sc = 1.0f;
    if (!last) { int oc = outcnt[node]; if (oc < 1) oc = 1; sc = rsqrtf((float)oc); }
    uint2 o;
    o.x = bf16rne(h0 * sc) | (bf16rne(h1 * sc) << 16);
    o.y = bf16rne(h2 * sc) | (bf16rne(h3 * sc) << 16);
    ((uint2*)g_out)[(size_t)node * 32 + lane] = o;
}

// bf16 MFMA MLP layer: out[N,128] = act(in[N,128] @ W[128,128] + b).
// Block = 256 thr (4 waves), 64-row tile, full K=128 and all 128 cols.
// Verified gfx950 layouts: A[m=lane&15][k=quad*8+j], B[k][n=lane&15],
// D col=lane&15, row=quad*4+reg.
#define ASTR 136
__global__ __launch_bounds__(256) void mlp_mfma_kernel(const unsigned short* __restrict__ in,
                                                       const float* __restrict__ W,
                                                       const float* __restrict__ bias,
                                                       void* __restrict__ outp,
                                                       int N, int mode) {  // mode0: gelu+bf16 out; mode1: f32 out
    __shared__ unsigned short As[64 * ASTR];    // 17.4 KB
    __shared__ unsigned short Bs[128 * ASTR];   // 34.8 KB
    int tid = threadIdx.x;
    int row0 = blockIdx.x * 64;
    // stage A: 64 rows x 128 bf16 (clamp rows >= N)
    for (int i = tid; i < 64 * 16; i += 256) {
        int r = i >> 4, c8 = i & 15;
        int gr = row0 + r; if (gr >= N) gr = N - 1;
        uint4 v = *(const uint4*)(in + (size_t)gr * DD + c8 * 8);
        *(uint4*)&As[r * ASTR + c8 * 8] = v;
    }
    // stage B transposed: Bs[n][k] = bf16(W[k][n])
    for (int i = tid; i < 128 * 128; i += 256) {
        int k = i >> 7, n = i & 127;
        Bs[n * ASTR + k] = (unsigned short)bf16rne(W[i]);
    }
    __syncthreads();

    int wv = tid >> 6, lane = tid & 63;
    int m = lane & 15, quad = lane >> 4;
    const unsigned short* arow = &As[(16 * wv + m) * ASTR + quad * 8];
    f32x4 acc[8];
#pragma unroll
    for (int t = 0; t < 8; t++) {
        const unsigned short* brow = &Bs[(t * 16 + m) * ASTR + quad * 8];
        f32x4 c = {0.f, 0.f, 0.f, 0.f};
#pragma unroll
        for (int s = 0; s < 4; s++) {
            short8 a = *(const short8*)(arow + s * 32);
            short8 b = *(const short8*)(brow + s * 32);
            c = __builtin_amdgcn_mfma_f32_16x16x32_bf16(a, b, c, 0, 0, 0);
        }
        acc[t] = c;
    }
#pragma unroll
    for (int t = 0; t < 8; t++) {
        float bv = bias[t * 16 + m];
#pragma unroll
        for (int r = 0; r < 4; r++) {
            int grow = row0 + 16 * wv + quad * 4 + r;
            if (grow >= N) continue;
            float v = acc[t][r] + bv;
            size_t oidx = (size_t)grow * DD + t * 16 + m;
            if (mode == 0) {
                v = 0.5f * v * (1.0f + erff(v * 0.70710678118654752f));
                ((unsigned short*)outp)[oidx] = (unsigned short)bf16rne(v);
            } else {
                ((float*)outp)[oidx] = v;
            }
        }
    }
}

extern "C" void kernel_launch(void* const* d_in, const int* in_sizes, int n_in,
                              void* d_out, int out_size, void* d_ws, size_t ws_size,
                              hipStream_t stream) {
    const float* feat = (const float*)d_in[0];
    const int*   e_feat = (const int*)d_in[1];
    const int*   src = (const int*)d_in[2];
    const int*   dst = (const int*)d_in[3];
    const float* emb = (const float*)d_in[4];
    const float* We1 = (const float*)d_in[5];
    const float* be1 = (const float*)d_in[6];
    const float* We2 = (const float*)d_in[7];
    const float* be2 = (const float*)d_in[8];
    const float* W1  = (const float*)d_in[9];
    const float* b1  = (const float*)d_in[10];
    const float* W2  = (const float*)d_in[11];
    const float* b2  = (const float*)d_in[12];
    float* out = (float*)d_out;

    const int N = NNODES, E = NEDGES;
    const int NBLK = (N + 255) / 256;     // 196 scan blocks
    char* ws = (char*)d_ws;
    size_t off = 0;
    unsigned* ga = (unsigned*)(ws + off);  off += (size_t)N * 256;        // 12.8 MB bf16 state
    unsigned* gb = (unsigned*)(ws + off);  off += (size_t)N * 256;        // 12.8 MB bf16 state
    int*   epay = (int*)(ws + off);        off += (size_t)E * 4;          // 6.4 MB
    int*   row_ptr = (int*)(ws + off);     off += (size_t)(N + 1) * 4;
    int*   excl = (int*)(ws + off);        off += (size_t)N * 4;
    int*   bsum = (int*)(ws + off);        off += 256 * 4;
    int*   cnts = (int*)(ws + off);        off += (size_t)2 * N * 4;      // incnt|outcnt
    int*   cnt_in = (int*)(ws + off);      off += (size_t)NSLICE * N * 4; // 12.8 MB partials
    int*   cnt_out = (int*)(ws + off);     off += (size_t)NSLICE * N * 4; // 12.8 MB partials
    int*   base_part = (int*)(ws + off);   off += (size_t)NSLICE * N * 4; // 12.8 MB bases
    float* gate = (float*)(ws + off);      off += 64;
    int* incnt  = cnts;
    int* outcnt = cnts + N;

    // No memsets needed: hist writes full partial slabs (incl. zeros).
    gate_kernel<<<1, 64, 0, stream>>>(emb, We1, be1, We2, be2, gate);
    dim3 hg(NSLICE, NRANGE);
    hist_kernel<<<hg, 256, 0, stream>>>(dst, cnt_in);
    hist_kernel<<<hg, 256, 0, stream>>>(src, cnt_out);
    reduce_kernel<<<(N + 255) / 256, 256, 0, stream>>>(cnt_in, cnt_out, incnt, outcnt, N);
    scan1_kernel<<<NBLK, 256, 0, stream>>>(incnt, excl, bsum, N);
    scan2_kernel<<<1, 256, 0, stream>>>(bsum, NBLK);
    scan3_kernel<<<(N + 256) / 256 + 1, 256, 0, stream>>>(excl, bsum, row_ptr, N, E);
    base_kernel<<<(N + 255) / 256, 256, 0, stream>>>(row_ptr, cnt_in, base_part, N);
    scatter2_kernel<<<hg, 256, 0, stream>>>(src, dst, e_feat, base_part, epay);
    scale_kernel<<<(N * 32 + 255) / 256, 256, 0, stream>>>(feat, outcnt, ga, N);

    const unsigned* gin = ga;
    unsigned* gout = gb;
    for (int k = 0; k < KHOPS; k++) {
        int last = (k == KHOPS - 1);
        hop_kernel<<<(N + 7) / 8, 256, 0, stream>>>(gin, feat, incnt, outcnt, gate,
                                                    row_ptr, epay, gout, N, last);
        gin = gout;
        gout = (gout == ga) ? gb : ga;
    }
    // Final h (unscaled, bf16) is in ga (hop9 writes ga); gb is free -> hidden.
    const unsigned short* hfin = (const unsigned short*)gin;
    unsigned short* hidden = (unsigned short*)gout;
    mlp_mfma_kernel<<<(N + 63) / 64, 256, 0, stream>>>(hfin, W1, b1, hidden, N, 0);
    mlp_mfma_kernel<<<(N + 63) / 64, 256, 0, stream>>>(hidden, W2, b2, out, N, 1);
}

// Round 6
// 769.825 us; speedup vs baseline: 1.7293x; 1.0600x over previous
//
#include <hip/hip_runtime.h>
#include <cmath>

// PropConv: K=10 hop gated propagation on a fixed graph + output MLP.
// R13: gate_kernel was the TOP dispatch (62us!) -- 8 active lanes on one CU,
// 4096 serially-dependent FMA+load iterations each (VALUBusy 0.011%).
// Parallelized: 256 threads = 8 etypes x 32 hidden units; thread (t,j) does
// the 128-elem dot (We1 reads coalesce across j-lanes), GELU, *We2[j]; then
// width-32 shfl_xor reduction -> gate[t]. ~dispatch-floor time.
// Preprocessing stays R12's zero-global-atomic LDS counting sort (816us run:
// deg/scatter no longer in top-5). Hops stay at the accepted L3 random-gather
// roofline: 410MB/hop / ~58us = 7.1TB/s, 256B/edge irreducible at bf16.

#define NNODES 50000
#define NEDGES 1600000
#define DD 128
#define KHOPS 10
#define ALPHA 0.1f

#define RS 16384          // node-range size (64KB LDS of int counters)
#define NRANGE 4          // ceil(50000/16384)
#define NSLICE 64         // edge slices
#define SLICE_E (NEDGES / NSLICE)   // 25000 edges/slice (100000B, 16B-aligned)

typedef short short8 __attribute__((ext_vector_type(8)));
typedef float f32x4 __attribute__((ext_vector_type(4)));

static __device__ __forceinline__ unsigned bf16rne(float x) {
    unsigned u = __float_as_uint(x);
    return (u + 0x7FFFu + ((u >> 16) & 1u)) >> 16;
}
static __device__ __forceinline__ float bf_lo(unsigned w) { return __uint_as_float(w << 16); }
static __device__ __forceinline__ float bf_hi(unsigned w) { return __uint_as_float(w & 0xFFFF0000u); }

// Parallel 8-entry gate table: thread (t = tid>>5, j = tid&31) computes
// hidden unit j of etype t; width-32 butterfly reduces g*We2 over j.
__global__ __launch_bounds__(256) void gate_kernel(const float* __restrict__ emb,
                                                   const float* __restrict__ We1,
                                                   const float* __restrict__ be1,
                                                   const float* __restrict__ We2,
                                                   const float* __restrict__ be2,
                                                   float* __restrict__ gate) {
    int tid = threadIdx.x;
    int t = tid >> 5, j = tid & 31;
    float a = be1[j];
#pragma unroll 8
    for (int k = 0; k < DD; k++)
        a += emb[t * DD + k] * We1[k * 32 + j];   // We1 row k: lanes j coalesce
    float g = 0.5f * a * (1.0f + erff(a * 0.70710678118654752f));  // exact GELU
    float p = g * We2[j];
#pragma unroll
    for (int m = 16; m >= 1; m >>= 1) p += __shfl_xor(p, m, 32);
    if (j == 0) gate[t] = 1.0f + 1.0f / (1.0f + expf(-(p + be2[0])));  // 1+sigmoid
}

// Pass1a: per-(range,slice) in-degree partial histogram via LDS atomics.
// cnt[b][n] written non-atomically (includes zeros -> no memset needed).
__global__ __launch_bounds__(256) void hist_kernel(const int* __restrict__ key,
                                                   int* __restrict__ cnt) {
    __shared__ int h[RS];
    int b = blockIdx.x, r = blockIdx.y;
    int lo = r * RS;
    int hi = lo + RS; if (hi > NNODES) hi = NNODES;
    for (int i = threadIdx.x; i < RS; i += 256) h[i] = 0;
    __syncthreads();
    const int4* p = (const int4*)(key + b * SLICE_E);
    for (int i = threadIdx.x; i < SLICE_E / 4; i += 256) {
        int4 v = p[i];
        if (v.x >= lo && v.x < hi) atomicAdd(&h[v.x - lo], 1);
        if (v.y >= lo && v.y < hi) atomicAdd(&h[v.y - lo], 1);
        if (v.z >= lo && v.z < hi) atomicAdd(&h[v.z - lo], 1);
        if (v.w >= lo && v.w < hi) atomicAdd(&h[v.w - lo], 1);
    }
    __syncthreads();
    int n = hi - lo;
    for (int i = threadIdx.x; i < n; i += 256)
        cnt[(size_t)b * NNODES + lo + i] = h[i];
}

// Totals: incnt/outcnt[n] = sum over slices of partials (coalesced slabs).
__global__ __launch_bounds__(256) void reduce_kernel(const int* __restrict__ cnt_in,
                                                     const int* __restrict__ cnt_out,
                                                     int* __restrict__ incnt,
                                                     int* __restrict__ outcnt, int N) {
    int n = blockIdx.x * 256 + threadIdx.x;
    if (n >= N) return;
    int a = 0, b = 0;
    for (int x = 0; x < NSLICE; x++) {
        a += cnt_in[(size_t)x * NNODES + n];
        b += cnt_out[(size_t)x * NNODES + n];
    }
    incnt[n] = a;
    outcnt[n] = b;
}

// ---- 3-kernel multi-block exclusive scan of incnt -> row_ptr ----
__global__ __launch_bounds__(256) void scan1_kernel(const int* __restrict__ cnt,
                                                    int* __restrict__ excl,
                                                    int* __restrict__ bsum, int N) {
    __shared__ int sh[256];
    int t = threadIdx.x;
    int g = blockIdx.x * 256 + t;
    int v = (g < N) ? cnt[g] : 0;
    sh[t] = v;
    __syncthreads();
    for (int off = 1; off < 256; off <<= 1) {
        int u = 0;
        if (t >= off) u = sh[t - off];
        __syncthreads();
        sh[t] += u;
        __syncthreads();
    }
    if (g < N) excl[g] = sh[t] - v;          // exclusive within block
    if (t == 255) bsum[blockIdx.x] = sh[255];
}
__global__ __launch_bounds__(256) void scan2_kernel(int* __restrict__ bsum, int nb) {
    __shared__ int sh[256];
    int t = threadIdx.x;
    int v = (t < nb) ? bsum[t] : 0;
    sh[t] = v;
    __syncthreads();
    for (int off = 1; off < 256; off <<= 1) {
        int u = 0;
        if (t >= off) u = sh[t - off];
        __syncthreads();
        sh[t] += u;
        __syncthreads();
    }
    if (t < nb) bsum[t] = sh[t] - v;         // exclusive
}
__global__ __launch_bounds__(256) void scan3_kernel(const int* __restrict__ excl,
                                                    const int* __restrict__ bsum,
                                                    int* __restrict__ row_ptr, int N, int E) {
    int g = blockIdx.x * 256 + threadIdx.x;
    if (g < N) row_ptr[g] = excl[g] + bsum[g >> 8];
    if (g == N) row_ptr[N] = E;
}

// Per-slice bucket bases: base_part[b][n] = row_ptr[n] + sum_{b'<b} cnt_in[b'][n].
// Sub-ranges partition each dst bucket deterministically by slice.
__global__ __launch_bounds__(256) void base_kernel(const int* __restrict__ row_ptr,
                                                   const int* __restrict__ cnt_in,
                                                   int* __restrict__ base_part, int N) {
    int n = blockIdx.x * 256 + threadIdx.x;
    if (n >= N) return;
    int run = row_ptr[n];
    for (int b = 0; b < NSLICE; b++) {
        base_part[(size_t)b * NNODES + n] = run;
        run += cnt_in[(size_t)b * NNODES + n];
    }
}

// Pass2: bucket edges by dst with LDS cursors -- zero global atomics.
// Payload: src (16b) | etype (<<16). Block (r,b) re-streams slice b; each
// in-range edge gets pos = lds_fetch_add(cursor[dst-lo]). Positions are
// unique: cursor range for (b,n) is exactly cnt_in[b][n] wide.
__global__ __launch_bounds__(256) void scatter2_kernel(const int* __restrict__ src,
                                                       const int* __restrict__ dst,
                                                       const int* __restrict__ ef,
                                                       const int* __restrict__ base_part,
                                                       int* __restrict__ epay) {
    __shared__ int cur[RS];
    int b = blockIdx.x, r = blockIdx.y;
    int lo = r * RS;
    int hi = lo + RS; if (hi > NNODES) hi = NNODES;
    int n = hi - lo;
    for (int i = threadIdx.x; i < n; i += 256)
        cur[i] = base_part[(size_t)b * NNODES + lo + i];
    __syncthreads();
    int off = b * SLICE_E;
    const int4* pd = (const int4*)(dst + off);
    const int4* ps = (const int4*)(src + off);
    const int4* pf = (const int4*)(ef + off);
    for (int i = threadIdx.x; i < SLICE_E / 4; i += 256) {
        int4 d = pd[i];
        int4 s = ps[i];
        int4 f = pf[i];
        int dv[4] = {d.x, d.y, d.z, d.w};
        int sv[4] = {s.x, s.y, s.z, s.w};
        int fv[4] = {f.x, f.y, f.z, f.w};
#pragma unroll
        for (int u = 0; u < 4; u++) {
            if (dv[u] >= lo && dv[u] < hi) {
                int pos = atomicAdd(&cur[dv[u] - lo], 1);
                epay[pos] = sv[u] | (fv[u] << 16);
            }
        }
    }
}

// g0 = bf16(feat * src_norm), row-major [N][128] bf16 (256B rows).
__global__ void scale_kernel(const float* __restrict__ feat, const int* __restrict__ outcnt,
                             unsigned* __restrict__ g0, int N) {
    int i = blockIdx.x * blockDim.x + threadIdx.x;   // one float4-group (4 cols)
    if (i >= N * 32) return;
    int row = i >> 5;
    int oc = outcnt[row]; if (oc < 1) oc = 1;
    float sn = rsqrtf((float)oc);
    float4 v = ((const float4*)feat)[i];
    uint2 o;
    o.x = bf16rne(v.x * sn) | (bf16rne(v.y * sn) << 16);
    o.y = bf16rne(v.z * sn) | (bf16rne(v.w * sn) << 16);
    ((uint2*)g0)[i] = o;
}

// Half-wave (32 lanes) per dst node; lane holds uint2 = 4 bf16 cols of the
// 256B row. Payloads loaded coalesced in chunks of 32, broadcast via __shfl;
// x8 unroll -> 8 independent 8B gathers in flight per lane. Epilogue in f32:
// h = .9*dstn*agg + .1*feat0; stores bf16(h*srcn); last hop stores bf16(h).
__global__ __launch_bounds__(256) void hop_kernel(const unsigned* __restrict__ g_in,
                                                  const float* __restrict__ feat0,
                                                  const int* __restrict__ incnt,
                                                  const int* __restrict__ outcnt,
                                                  const float* __restrict__ gate_g,
                                                  const int* __restrict__ row_ptr,
                                                  const int* __restrict__ epay,
                                                  unsigned* __restrict__ g_out,
                                                  int N, int last) {
    __shared__ float gateL[8];
    if (threadIdx.x < 8) gateL[threadIdx.x] = gate_g[threadIdx.x];
    __syncthreads();
    int half = threadIdx.x >> 5;     // 0..7
    int lane = threadIdx.x & 31;
    int node = blockIdx.x * 8 + half;
    if (node >= N) return;
    int beg = row_ptr[node], end = row_ptr[node + 1];
    const uint2* gp = (const uint2*)g_in;            // row = 32 uint2
    float a0 = 0.f, a1 = 0.f, a2 = 0.f, a3 = 0.f;
    for (int base = beg; base < end; base += 32) {
        int n = end - base; if (n > 32) n = 32;
        int p = 0;
        if (lane < n) p = epay[base + lane];
        int j = 0;
        for (; j + 8 <= n; j += 8) {
            int pj[8];
#pragma unroll
            for (int u = 0; u < 8; u++) pj[u] = __shfl(p, j + u, 32);
            uint2 v[8];
#pragma unroll
            for (int u = 0; u < 8; u++)
                v[u] = gp[(size_t)(pj[u] & 0xFFFF) * 32 + lane];
#pragma unroll
            for (int u = 0; u < 8; u++) {
                float c = gateL[(unsigned)pj[u] >> 16];
                a0 += c * bf_lo(v[u].x); a1 += c * bf_hi(v[u].x);
                a2 += c * bf_lo(v[u].y); a3 += c * bf_hi(v[u].y);
            }
        }
        for (; j < n; j++) {
            int pj = __shfl(p, j, 32);
            float c = gateL[(unsigned)pj >> 16];
            uint2 v = gp[(size_t)(pj & 0xFFFF) * 32 + lane];
            a0 += c * bf_lo(v.x); a1 += c * bf_hi(v.x);
            a2 += c * bf_lo(v.y); a3 += c * bf_hi(v.y);
        }
    }
    int ic = incnt[node]; if (ic < 1) ic = 1;
    float dn = rsqrtf((float)ic) * (1.0f - ALPHA);
    float4 fv = *(const float4*)(feat0 + (size_t)node * DD + lane * 4);
    float h0 = dn * a0 + ALPHA * fv.x;
    float h1 = dn * a1 + ALPHA * fv.y;
    float h2 = dn * a2 + ALPHA * fv.z;
    float h3 = dn * a3 + ALPHA * fv.w;
    float sc = 1.0f;
    if (!last) { int oc = outcnt[node]; if (oc < 1) oc = 1; sc = rsqrtf((float)oc); }
    uint2 o;
    o.x = bf16rne(h0 * sc) | (bf16rne(h1 * sc) << 16);
    o.y = bf16rne(h2 * sc) | (bf16rne(h3 * sc) << 16);
    ((uint2*)g_out)[(size_t)node * 32 + lane] = o;
}

// bf16 MFMA MLP layer: out[N,128] = act(in[N,128] @ W[128,128] + b).
// Block = 256 thr (4 waves), 64-row tile, full K=128 and all 128 cols.
// Verified gfx950 layouts: A[m=lane&15][k=quad*8+j], B[k][n=lane&15],
// D col=lane&15, row=quad*4+reg.
#define ASTR 136
__global__ __launch_bounds__(256) void mlp_mfma_kernel(const unsigned short* __restrict__ in,
                                                       const float* __restrict__ W,
                                                       const float* __restrict__ bias,
                                                       void* __restrict__ outp,
                                                       int N, int mode) {  // mode0: gelu+bf16 out; mode1: f32 out
    __shared__ unsigned short As[64 * ASTR];    // 17.4 KB
    __shared__ unsigned short Bs[128 * ASTR];   // 34.8 KB
    int tid = threadIdx.x;
    int row0 = blockIdx.x * 64;
    // stage A: 64 rows x 128 bf16 (clamp rows >= N)
    for (int i = tid; i < 64 * 16; i += 256) {
        int r = i >> 4, c8 = i & 15;
        int gr = row0 + r; if (gr >= N) gr = N - 1;
        uint4 v = *(const uint4*)(in + (size_t)gr * DD + c8 * 8);
        *(uint4*)&As[r * ASTR + c8 * 8] = v;
    }
    // stage B transposed: Bs[n][k] = bf16(W[k][n])
    for (int i = tid; i < 128 * 128; i += 256) {
        int k = i >> 7, n = i & 127;
        Bs[n * ASTR + k] = (unsigned short)bf16rne(W[i]);
    }
    __syncthreads();

    int wv = tid >> 6, lane = tid & 63;
    int m = lane & 15, quad = lane >> 4;
    const unsigned short* arow = &As[(16 * wv + m) * ASTR + quad * 8];
    f32x4 acc[8];
#pragma unroll
    for (int t = 0; t < 8; t++) {
        const unsigned short* brow = &Bs[(t * 16 + m) * ASTR + quad * 8];
        f32x4 c = {0.f, 0.f, 0.f, 0.f};
#pragma unroll
        for (int s = 0; s < 4; s++) {
            short8 a = *(const short8*)(arow + s * 32);
            short8 b = *(const short8*)(brow + s * 32);
            c = __builtin_amdgcn_mfma_f32_16x16x32_bf16(a, b, c, 0, 0, 0);
        }
        acc[t] = c;
    }
#pragma unroll
    for (int t = 0; t < 8; t++) {
        float bv = bias[t * 16 + m];
#pragma unroll
        for (int r = 0; r < 4; r++) {
            int grow = row0 + 16 * wv + quad * 4 + r;
            if (grow >= N) continue;
            float v = acc[t][r] + bv;
            size_t oidx = (size_t)grow * DD + t * 16 + m;
            if (mode == 0) {
                v = 0.5f * v * (1.0f + erff(v * 0.70710678118654752f));
                ((unsigned short*)outp)[oidx] = (unsigned short)bf16rne(v);
            } else {
                ((float*)outp)[oidx] = v;
            }
        }
    }
}

extern "C" void kernel_launch(void* const* d_in, const int* in_sizes, int n_in,
                              void* d_out, int out_size, void* d_ws, size_t ws_size,
                              hipStream_t stream) {
    const float* feat = (const float*)d_in[0];
    const int*   e_feat = (const int*)d_in[1];
    const int*   src = (const int*)d_in[2];
    const int*   dst = (const int*)d_in[3];
    const float* emb = (const float*)d_in[4];
    const float* We1 = (const float*)d_in[5];
    const float* be1 = (const float*)d_in[6];
    const float* We2 = (const float*)d_in[7];
    const float* be2 = (const float*)d_in[8];
    const float* W1  = (const float*)d_in[9];
    const float* b1  = (const float*)d_in[10];
    const float* W2  = (const float*)d_in[11];
    const float* b2  = (const float*)d_in[12];
    float* out = (float*)d_out;

    const int N = NNODES, E = NEDGES;
    const int NBLK = (N + 255) / 256;     // 196 scan blocks
    char* ws = (char*)d_ws;
    size_t off = 0;
    unsigned* ga = (unsigned*)(ws + off);  off += (size_t)N * 256;        // 12.8 MB bf16 state
    unsigned* gb = (unsigned*)(ws + off);  off += (size_t)N * 256;        // 12.8 MB bf16 state
    int*   epay = (int*)(ws + off);        off += (size_t)E * 4;          // 6.4 MB
    int*   row_ptr = (int*)(ws + off);     off += (size_t)(N + 1) * 4;
    int*   excl = (int*)(ws + off);        off += (size_t)N * 4;
    int*   bsum = (int*)(ws + off);        off += 256 * 4;
    int*   cnts = (int*)(ws + off);        off += (size_t)2 * N * 4;      // incnt|outcnt
    int*   cnt_in = (int*)(ws + off);      off += (size_t)NSLICE * N * 4; // 12.8 MB partials
    int*   cnt_out = (int*)(ws + off);     off += (size_t)NSLICE * N * 4; // 12.8 MB partials
    int*   base_part = (int*)(ws + off);   off += (size_t)NSLICE * N * 4; // 12.8 MB bases
    float* gate = (float*)(ws + off);      off += 64;
    int* incnt  = cnts;
    int* outcnt = cnts + N;

    // No memsets needed: hist writes full partial slabs (incl. zeros).
    gate_kernel<<<1, 256, 0, stream>>>(emb, We1, be1, We2, be2, gate);
    dim3 hg(NSLICE, NRANGE);
    hist_kernel<<<hg, 256, 0, stream>>>(dst, cnt_in);
    hist_kernel<<<hg, 256, 0, stream>>>(src, cnt_out);
    reduce_kernel<<<(N + 255) / 256, 256, 0, stream>>>(cnt_in, cnt_out, incnt, outcnt, N);
    scan1_kernel<<<NBLK, 256, 0, stream>>>(incnt, excl, bsum, N);
    scan2_kernel<<<1, 256, 0, stream>>>(bsum, NBLK);
    scan3_kernel<<<(N + 256) / 256 + 1, 256, 0, stream>>>(excl, bsum, row_ptr, N, E);
    base_kernel<<<(N + 255) / 256, 256, 0, stream>>>(row_ptr, cnt_in, base_part, N);
    scatter2_kernel<<<hg, 256, 0, stream>>>(src, dst, e_feat, base_part, epay);
    scale_kernel<<<(N * 32 + 255) / 256, 256, 0, stream>>>(feat, outcnt, ga, N);

    const unsigned* gin = ga;
    unsigned* gout = gb;
    for (int k = 0; k < KHOPS; k++) {
        int last = (k == KHOPS - 1);
        hop_kernel<<<(N + 7) / 8, 256, 0, stream>>>(gin, feat, incnt, outcnt, gate,
                                                    row_ptr, epay, gout, N, last);
        gin = gout;
        gout = (gout == ga) ? gb : ga;
    }
    // Final h (unscaled, bf16) is in ga (hop9 writes ga); gb is free -> hidden.
    const unsigned short* hfin = (const unsigned short*)gin;
    unsigned short* hidden = (unsigned short*)gout;
    mlp_mfma_kernel<<<(N + 63) / 64, 256, 0, stream>>>(hfin, W1, b1, hidden, N, 0);
    mlp_mfma_kernel<<<(N + 63) / 64, 256, 0, stream>>>(hidden, W2, b2, out, N, 1);
}